// Round 10
// baseline (894.297 us; speedup 1.0000x reference)
//
#include <hip/hip_runtime.h>

#define BB 512
#define SS 256
#define HH 128
#define NC 10

typedef _Float16 v8h __attribute__((ext_vector_type(8)));
typedef float    v4f __attribute__((ext_vector_type(4)));

// =====================================================================
// proj_k: out[m][j] = sum_d A[m][d] * W[j][d]   (bias-free; scan adds it)
// Used only for layer 0 (K=28).
// =====================================================================
template<int K>
__global__ __launch_bounds__(256, 1)
void proj_k(const float* __restrict__ A, const float* __restrict__ W,
            float* __restrict__ out)
{
    constexpr int AS = ((K + 31) / 32) * 32 + 4;
    constexpr int KQ = K / 4;
    constexpr int KCW = (K < 32) ? K : 32;
    constexpr int WQ = KCW / 4;
    const int tid = threadIdx.x;
    const int tx = tid & 15;
    const int ty = tid >> 4;
    const size_t m0 = (size_t)blockIdx.x * 64;

    __shared__ float Arm[64 * AS];
    __shared__ float Wst[128 * 36];

    for (int idx = tid; idx < 64 * KQ; idx += 256) {
        const int row = idx / KQ, kq = idx % KQ;
        const float4 v = *(const float4*)(A + (m0 + row) * K + 4 * kq);
        *(float4*)(&Arm[row * AS + 4 * kq]) = v;
    }

    float acc[4][8];
    #pragma unroll
    for (int c = 0; c < 8; ++c)
        #pragma unroll
        for (int r = 0; r < 4; ++r) acc[r][c] = 0.f;

    #pragma unroll 1
    for (int kc = 0; kc < K; kc += KCW) {
        __syncthreads();
        for (int idx = tid; idx < 128 * WQ; idx += 256) {
            const int col = idx / WQ, q = idx % WQ;
            const float4 v = *(const float4*)(W + (size_t)col * K + kc + 4 * q);
            *(float4*)(&Wst[col * 36 + 4 * q]) = v;
        }
        __syncthreads();
        #pragma unroll 2
        for (int q = 0; q < WQ; ++q) {
            float4 av[4];
            #pragma unroll
            for (int r = 0; r < 4; ++r)
                av[r] = *(const float4*)(&Arm[(ty + 16 * r) * AS + kc + 4 * q]);
            #pragma unroll
            for (int c = 0; c < 8; ++c) {
                const float4 wv = *(const float4*)(&Wst[(tx + 16 * c) * 36 + 4 * q]);
                #pragma unroll
                for (int r = 0; r < 4; ++r)
                    acc[r][c] += av[r].x * wv.x + av[r].y * wv.y
                               + av[r].z * wv.z + av[r].w * wv.w;
            }
        }
    }

    #pragma unroll
    for (int r = 0; r < 4; ++r)
        #pragma unroll
        for (int c = 0; c < 8; ++c)
            out[(m0 + ty + 16 * r) * HH + tx + 16 * c] = acc[r][c];
}

// =====================================================================
// scan_mfma (R10): 16 batch rows per block, 4 waves, 32 blocks.
// Per step: h_s[16x128] = tanh(xw_l[s] + h_{s-1} @ W_hh^T) on matrix
// cores via f16 hi/lo split (3-term: Ahi*Bhi + Alo*Bhi + Ahi*Blo).
// Wave w owns cols [32w, 32w+32) = 2 n-tiles; K = 4 k-tiles.
// Fragment layouts (16x16x32, doc-verified):
//   A[m=lane&15][k=quad*8+j]   B[k=quad*8+j][n=lane&15]   (B[k][n]=W[n][k])
//   C/D: col=lane&15, row=quad*4+reg
// h ping-pong in LDS as separate hi/lo f16 arrays, row stride 136
// (2-way banks = free). xw prefetched 2 steps ahead straight from
// global into 8 regs. Fused 2-term projection of h_{s-1} with
// W_ih_next rides on the same A-fragments and stores straight to buf.
// 1 wave/SIMD (waves_per_eu(1,1)) -> 512-reg budget, no demotion.
// In-place: buf slice s read (prefetch) at step s-2, written (xw_next)
// at step s+1 -> strictly ordered by the per-step barrier.
// =====================================================================
template<bool LAST>
__global__ __attribute__((amdgpu_flat_work_group_size(256, 256),
                          amdgpu_waves_per_eu(1, 1)))
void scan_mfma(float* __restrict__ buf, float* __restrict__ hfin,
               const float* __restrict__ w_hh, const float* __restrict__ w_ih,
               const float* __restrict__ b_ih_l, const float* __restrict__ b_hh_l)
{
    const int tid  = threadIdx.x;
    const int w    = tid >> 6;
    const int lane = tid & 63;
    const int l15  = lane & 15;
    const int quad = lane >> 4;
    const int b0   = blockIdx.x * 16;

    __shared__ __align__(16) _Float16 AH[2][2][16][136]; // [buf][hi/lo][m][k]

    {   // zero h_{-1} (buffer 0, hi+lo)
        uint32_t* zp = (uint32_t*)&AH[0][0][0][0];
        for (int i = tid; i < (2 * 16 * 136) / 2; i += 256) zp[i] = 0u;
    }

    int coln[2]; float bias[2];
    #pragma unroll
    for (int nt = 0; nt < 2; ++nt) {
        coln[nt] = 32 * w + 16 * nt + l15;
        bias[nt] = b_ih_l[coln[nt]] + b_hh_l[coln[nt]];
    }

    // B fragments: W_hh hi+lo, W_ih hi
    v8h bhh[2][4], bhl[2][4], bih[2][4];
    #pragma unroll
    for (int nt = 0; nt < 2; ++nt) {
        #pragma unroll
        for (int kt = 0; kt < 4; ++kt) {
            const float* ph = w_hh + (size_t)coln[nt] * HH + kt * 32 + quad * 8;
            v8h hi, lo;
            #pragma unroll
            for (int i = 0; i < 8; ++i) {
                const float x = ph[i];
                const _Float16 h = (_Float16)x;
                hi[i] = h; lo[i] = (_Float16)(x - (float)h);
            }
            bhh[nt][kt] = hi; bhl[nt][kt] = lo;
            if (!LAST) {
                const float* pi = w_ih + (size_t)coln[nt] * HH + kt * 32 + quad * 8;
                v8h ih;
                #pragma unroll
                for (int i = 0; i < 8; ++i) ih[i] = (_Float16)pi[i];
                bih[nt][kt] = ih;
            }
        }
    }

    // xw addressing: value (q,nt) lives at buf[(b0+quad*4+q)*SS*HH + s*HH + coln[nt]]
    size_t rb[8];
    #pragma unroll
    for (int nt = 0; nt < 2; ++nt)
        #pragma unroll
        for (int q = 0; q < 4; ++q)
            rb[nt * 4 + q] = ((size_t)(b0 + quad * 4 + q) * SS) * HH + coln[nt];

    float xwA[8], xwB[8];
    #pragma unroll
    for (int i = 0; i < 8; ++i) {
        xwA[i] = buf[rb[i]];
        xwB[i] = buf[rb[i] + HH];
    }
    __syncthreads();

#define SUBSTEP(S, CUR, NXT, XW)                                               \
    {                                                                          \
        v8h ah[4], al[4];                                                      \
        _Pragma("unroll")                                                      \
        for (int kt = 0; kt < 4; ++kt) {                                       \
            ah[kt] = *(const v8h*)&AH[CUR][0][l15][kt * 32 + quad * 8];        \
            al[kt] = *(const v8h*)&AH[CUR][1][l15][kt * 32 + quad * 8];        \
        }                                                                      \
        if (!LAST) {  /* fused projection of h_{S-1} (2-term) */               \
            _Pragma("unroll")                                                  \
            for (int nt = 0; nt < 2; ++nt) {                                   \
                v4f c2 = {0.f, 0.f, 0.f, 0.f};                                 \
                _Pragma("unroll")                                              \
                for (int kt = 0; kt < 4; ++kt) {                               \
                    c2 = __builtin_amdgcn_mfma_f32_16x16x32_f16(ah[kt], bih[nt][kt], c2, 0, 0, 0); \
                    c2 = __builtin_amdgcn_mfma_f32_16x16x32_f16(al[kt], bih[nt][kt], c2, 0, 0, 0); \
                }                                                              \
                if ((S) > 0) {                                                 \
                    _Pragma("unroll")                                          \
                    for (int q = 0; q < 4; ++q)                                \
                        buf[rb[nt * 4 + q] + (size_t)((S) - 1) * HH] = c2[q];  \
                }                                                              \
            }                                                                  \
        }                                                                      \
        float hv[8];                                                           \
        _Pragma("unroll")                                                      \
        for (int nt = 0; nt < 2; ++nt) {  /* recurrence (3-term) */            \
            v4f c = {0.f, 0.f, 0.f, 0.f};                                      \
            _Pragma("unroll")                                                  \
            for (int kt = 0; kt < 4; ++kt) {                                   \
                c = __builtin_amdgcn_mfma_f32_16x16x32_f16(ah[kt], bhh[nt][kt], c, 0, 0, 0); \
                c = __builtin_amdgcn_mfma_f32_16x16x32_f16(al[kt], bhh[nt][kt], c, 0, 0, 0); \
                c = __builtin_amdgcn_mfma_f32_16x16x32_f16(ah[kt], bhl[nt][kt], c, 0, 0, 0); \
            }                                                                  \
            _Pragma("unroll")                                                  \
            for (int q = 0; q < 4; ++q) {                                      \
                const float z = c[q] + XW[nt * 4 + q] + bias[nt];              \
                const float e = __expf(2.f * z);                               \
                hv[nt * 4 + q] = 1.f - 2.f * __builtin_amdgcn_rcpf(1.f + e);   \
            }                                                                  \
        }                                                                      \
        _Pragma("unroll")                                                      \
        for (int nt = 0; nt < 2; ++nt)  /* h_S -> LDS (hi/lo) */               \
            _Pragma("unroll")                                                  \
            for (int q = 0; q < 4; ++q) {                                      \
                const float x = hv[nt * 4 + q];                                \
                const _Float16 h = (_Float16)x;                                \
                AH[NXT][0][quad * 4 + q][coln[nt]] = h;                        \
                AH[NXT][1][quad * 4 + q][coln[nt]] = (_Float16)(x - (float)h); \
            }                                                                  \
        if (LAST && (S) == SS - 1) {                                           \
            _Pragma("unroll")                                                  \
            for (int nt = 0; nt < 2; ++nt)                                     \
                _Pragma("unroll")                                              \
                for (int q = 0; q < 4; ++q)                                    \
                    hfin[(size_t)(b0 + quad * 4 + q) * HH + coln[nt]] = hv[nt * 4 + q]; \
        }                                                                      \
        if ((S) + 2 < SS) {                                                    \
            _Pragma("unroll")                                                  \
            for (int i = 0; i < 8; ++i)                                        \
                XW[i] = buf[rb[i] + (size_t)((S) + 2) * HH];                   \
        }                                                                      \
        __syncthreads();                                                       \
    }

    for (int s2 = 0; s2 < SS; s2 += 2) {
        SUBSTEP(s2,     0, 1, xwA)
        SUBSTEP(s2 + 1, 1, 0, xwB)
    }
#undef SUBSTEP

    if (!LAST) {   // projection of h_{SS-1} (sits in AH[0])
        v8h ah[4], al[4];
        #pragma unroll
        for (int kt = 0; kt < 4; ++kt) {
            ah[kt] = *(const v8h*)&AH[0][0][l15][kt * 32 + quad * 8];
            al[kt] = *(const v8h*)&AH[0][1][l15][kt * 32 + quad * 8];
        }
        #pragma unroll
        for (int nt = 0; nt < 2; ++nt) {
            v4f c2 = {0.f, 0.f, 0.f, 0.f};
            #pragma unroll
            for (int kt = 0; kt < 4; ++kt) {
                c2 = __builtin_amdgcn_mfma_f32_16x16x32_f16(ah[kt], bih[nt][kt], c2, 0, 0, 0);
                c2 = __builtin_amdgcn_mfma_f32_16x16x32_f16(al[kt], bih[nt][kt], c2, 0, 0, 0);
            }
            #pragma unroll
            for (int q = 0; q < 4; ++q)
                buf[rb[nt * 4 + q] + (size_t)(SS - 1) * HH] = c2[q];
        }
    }
}

// =====================================================================
__global__ __launch_bounds__(128)
void fc_k(const float* __restrict__ hlast, const float* __restrict__ fc_w,
          const float* __restrict__ fc_b, float* __restrict__ out)
{
    const int b = blockIdx.x;
    const int tid = threadIdx.x;
    __shared__ __align__(16) float h[HH];
    h[tid] = hlast[(size_t)b * HH + tid];
    __syncthreads();
    if (tid < NC) {
        float a = fc_b[tid];
        const float* wr = fc_w + tid * HH;
        #pragma unroll 4
        for (int k = 0; k < HH; ++k) a += h[k] * wr[k];
        out[(size_t)b * NC + tid] = a;
    }
}

extern "C" void kernel_launch(void* const* d_in, const int* in_sizes, int n_in,
                              void* d_out, int out_size, void* d_ws, size_t ws_size,
                              hipStream_t stream) {
    const float* x     = (const float*)d_in[0];   // (512,256,28)
    const float* w_ih0 = (const float*)d_in[1];   // (128,28)
    const float* w_hh0 = (const float*)d_in[2];   // (128,128)
    const float* b_ih0 = (const float*)d_in[3];
    const float* b_hh0 = (const float*)d_in[4];
    const float* w_ih  = (const float*)d_in[5];   // (3,128,128)
    const float* w_hh  = (const float*)d_in[6];   // (3,128,128)
    const float* b_ih  = (const float*)d_in[7];   // (3,128)
    const float* b_hh  = (const float*)d_in[8];
    const float* fc_w  = (const float*)d_in[9];   // (10,128)
    const float* fc_b  = (const float*)d_in[10];
    float* out = (float*)d_out;

    float* buf  = (float*)d_ws;                   // (B,S,H) fp32 = 64 MB
    float* hfin = buf + (size_t)BB * SS * HH;     // (B,H)

    // layer 0 input projection (bias-free)
    proj_k<28><<<(BB * SS) / 64, 256, 0, stream>>>(x, w_ih0, buf);
    // layer 0..3 scans on matrix cores; each non-last fuses the next
    // layer's input projection
    scan_mfma<false><<<32, 256, 0, stream>>>(buf, hfin, w_hh0, w_ih,
                                             b_ih0, b_hh0);
    scan_mfma<false><<<32, 256, 0, stream>>>(buf, hfin, w_hh,
                                             w_ih + (size_t)1 * HH * HH,
                                             b_ih, b_hh);
    scan_mfma<false><<<32, 256, 0, stream>>>(buf, hfin, w_hh + (size_t)1 * HH * HH,
                                             w_ih + (size_t)2 * HH * HH,
                                             b_ih + HH, b_hh + HH);
    scan_mfma<true><<<32, 256, 0, stream>>>(buf, hfin, w_hh + (size_t)2 * HH * HH,
                                            nullptr, b_ih + 2 * HH, b_hh + 2 * HH);
    fc_k<<<BB, 128, 0, stream>>>(hfin, fc_w, fc_b, out);
}